// Round 1
// baseline (450.150 us; speedup 1.0000x reference)
//
#include <hip/hip_runtime.h>
#include <math.h>
#include <stdint.h>

#define B_ 2
#define H_ 8
#define C_ 2048
#define E_ 1024
#define D_ 64
#define KP_ 8
#define P_ 16
#define HD_ 512              // H*D
#define ROWS_ 32768          // B*H*C
#define M_ 4096              // B*C

typedef __bf16 bf16x8 __attribute__((ext_vector_type(8)));
typedef float f32x4 __attribute__((ext_vector_type(4)));
typedef uint16_t u16x8 __attribute__((ext_vector_type(8)));

__device__ inline uint16_t f2bf(float f) {
    union { float f; uint32_t u; } v; v.f = f;
    uint32_t u = v.u + 0x7FFF + ((v.u >> 16) & 1);   // RNE
    return (uint16_t)(u >> 16);
}
__device__ inline float bf2f(uint16_t h) {
    union { uint32_t u; float f; } v; v.u = ((uint32_t)h) << 16;
    return v.f;
}

// async global->LDS, 16B per lane; LDS dest = wave-uniform base + lane*16
__device__ inline void gload16(const uint16_t* g, uint16_t* l) {
    __builtin_amdgcn_global_load_lds(
        (const __attribute__((address_space(1))) void*)g,
        (__attribute__((address_space(3))) void*)l, 16, 0, 0);
}

// ---------------------------------------------------------------------------
// prep kernel: x-convert, weight transpose-convert, density context-sums.
//   blocks [0, 2048)      : convert x (fp32 -> bf16), 8 elem/thread
//   blocks [2048, 4096)   : transpose-convert one 32x32 weight tile
//   blocks [4096, 4224)   : density sums (one thread per (b,h,c) row)
// ---------------------------------------------------------------------------
__global__ __launch_bounds__(256) void prep_kernel(
    const float* __restrict__ x,
    const float* __restrict__ Wq, const float* __restrict__ Wk,
    const float* __restrict__ Wv, const float* __restrict__ Wu,
    const float* __restrict__ means, const float* __restrict__ sigmas,
    uint16_t* __restrict__ xb, uint16_t* __restrict__ Wall,
    uint16_t* __restrict__ Wut, float* __restrict__ S)
{
    const int bx = blockIdx.x;
    if (bx < 2048) {
        const int i = (bx * 256 + threadIdx.x) * 8;
        const float4 a = *(const float4*)(x + i);
        const float4 b = *(const float4*)(x + i + 4);
        u16x8 o;
        o[0] = f2bf(a.x); o[1] = f2bf(a.y); o[2] = f2bf(a.z); o[3] = f2bf(a.w);
        o[4] = f2bf(b.x); o[5] = f2bf(b.y); o[6] = f2bf(b.z); o[7] = f2bf(b.w);
        *(u16x8*)(xb + i) = o;
        return;
    }
    if (bx < 4096) {
        const int t = bx - 2048;
        const int z = t >> 9;
        const float* in; uint16_t* out; int R, Cc; float scale;
        if (z == 0)      { in = Wq; out = Wall;               R = E_;  Cc = HD_; scale = 0.125f; }
        else if (z == 1) { in = Wk; out = Wall + 512 * 1024;  R = E_;  Cc = HD_; scale = 0.125f; }
        else if (z == 2) { in = Wv; out = Wall + 1024 * 1024; R = E_;  Cc = HD_; scale = 1.0f; }
        else             { in = Wu; out = Wut;                R = HD_; Cc = E_;  scale = 1.0f; }
        const int tiles_x = Cc >> 5;
        const int ti = t & 511;
        const int tx = ti % tiles_x;
        const int ty = ti / tiles_x;
        const int r0 = ty * 32, c0 = tx * 32;
        __shared__ float tbuf[32][33];
        const int lx = threadIdx.x & 31, ly = threadIdx.x >> 5;
#pragma unroll
        for (int i = 0; i < 4; ++i)
            tbuf[ly * 4 + i][lx] = in[(size_t)(r0 + ly * 4 + i) * Cc + c0 + lx];
        __syncthreads();
#pragma unroll
        for (int i = 0; i < 4; ++i)
            out[(size_t)(c0 + ly * 4 + i) * R + r0 + lx] =
                f2bf(tbuf[lx][ly * 4 + i] * scale);
        return;
    }
    // ---- density sums ----
    const int row = (bx - 4096) * 256 + threadIdx.x;
    const int lane = threadIdx.x & 63;
    const int bh = row >> 11;

    const float* mrow = means + (size_t)row * 8;
    const float* srow = sigmas + (size_t)row * 8;
    const float4 ma = *(const float4*)(mrow);
    const float4 mb = *(const float4*)(mrow + 4);
    const float4 sa = *(const float4*)(srow);
    const float4 sb = *(const float4*)(srow + 4);
    const float mm[8] = {ma.x, ma.y, ma.z, ma.w, mb.x, mb.y, mb.z, mb.w};
    const float sg[8] = {sa.x, sa.y, sa.z, sa.w, sb.x, sb.y, sb.z, sb.w};

    int idx[16];
#pragma unroll
    for (int j = 0; j < 8; ++j) {
        int i0 = (int)floorf(mm[j]);
        i0 = min(max(i0, 0), C_ - 1);
        idx[2 * j] = i0;
        idx[2 * j + 1] = min(i0 + 1, C_ - 1);
    }
    unsigned dupm = 0;
#pragma unroll
    for (int p = 1; p < 16; ++p) {
        bool d = false;
#pragma unroll
        for (int q = 0; q < 15; ++q)
            if (q < p) d = d || (idx[q] == idx[p]);
        if (d) dupm |= (1u << p);
    }
#pragma unroll
    for (int p = 0; p < 16; ++p) {
        const float fi = (float)idx[p];
        const bool dup = (dupm >> p) & 1u;
#pragma unroll
        for (int kk = 0; kk < 8; ++kk) {
            const float t = (fi - mm[kk]) / sg[kk];
            float val = dup ? 0.0f : expf(-0.5f * t * t);
#pragma unroll
            for (int off = 1; off < 64; off <<= 1)
                val += __shfl_xor(val, off);
            if (lane == 0)
                atomicAdd(&S[bh * 128 + p * 8 + kk], val);
        }
    }
}

// ---------------------------------------------------------------------------
// Fused QKV GEMM (MFMA bf16), 128x64 tiles -> 24x32 = 768 blocks (3.0/CU).
// N-tile = 64 = exactly one head: epilogue rows are 128B-contiguous in Out.
// ---------------------------------------------------------------------------
__global__ __launch_bounds__(256) void gemm_qkv_kernel(
    const uint16_t* __restrict__ xb, const uint16_t* __restrict__ Wall,
    uint16_t* __restrict__ Qt, uint16_t* __restrict__ Kt,
    uint16_t* __restrict__ Vt)
{
    const int K = E_;                       // 1024
    const int m0 = blockIdx.y * 128;
    const int n0 = blockIdx.x * 64;         // 0..1535
    const int z = n0 >> 9;
    uint16_t* __restrict__ Out = (z == 0) ? Qt : (z == 1) ? Kt : Vt;
    const int h = (n0 & 511) >> 6;          // single head per block

    // K-loop: As = smem[0..4096), Bs = smem[4096..6144)
    // epilogue: 128 x 72-stride bf16 tile in smem[0..9216)
    __shared__ __align__(16) uint16_t smem[9216];
    uint16_t* As = smem;
    uint16_t* Bs = smem + 4096;

    const int tid = threadIdx.x;
    const int w = tid >> 6, lane = tid & 63;

    f32x4 acc[2][4] = {};

    // staging: 12 chunks of 16 rows (8 A-chunks + 4 B-chunks); wave w: 3w..3w+2
    const uint16_t* gP[3];
    uint16_t* lP[3];
#pragma unroll
    for (int j = 0; j < 3; ++j) {
        const int ci = w * 3 + j;
        const int rr = (ci & 7) * 16 + (lane >> 2);   // works for both halves
        const int ko = (lane & 3) * 8;
        if (ci < 8) {
            gP[j] = xb + (size_t)(m0 + rr) * K + ko;
            lP[j] = &As[ci * 512];
        } else {
            const int cb = ci - 8;
            gP[j] = Wall + (size_t)(n0 + cb * 16 + (lane >> 2)) * K + ko;
            lP[j] = &Bs[cb * 512];
        }
    }

    const int fr = lane & 15;
    const int fk = (lane >> 4) * 8;

    for (int k0 = 0; k0 < K; k0 += 32) {
        __syncthreads();
        gload16(gP[0] + k0, lP[0]);
        gload16(gP[1] + k0, lP[1]);
        gload16(gP[2] + k0, lP[2]);
        __syncthreads();
        bf16x8 af[2], bf[4];
#pragma unroll
        for (int mt = 0; mt < 2; ++mt)
            af[mt] = *(const bf16x8*)&As[(w * 32 + mt * 16 + fr) * 32 + fk];
#pragma unroll
        for (int nt = 0; nt < 4; ++nt)
            bf[nt] = *(const bf16x8*)&Bs[(nt * 16 + fr) * 32 + fk];
#pragma unroll
        for (int mt = 0; mt < 2; ++mt)
#pragma unroll
            for (int nt = 0; nt < 4; ++nt)
                acc[mt][nt] = __builtin_amdgcn_mfma_f32_16x16x32_bf16(
                    af[mt], bf[nt], acc[mt][nt], 0, 0, 0);
    }

    // ---- epilogue: stage 128x64 bf16 tile (stride 72), stream coalesced ----
    __syncthreads();
#pragma unroll
    for (int mt = 0; mt < 2; ++mt)
#pragma unroll
        for (int nt = 0; nt < 4; ++nt) {
            const int col = nt * 16 + fr;
#pragma unroll
            for (int r = 0; r < 4; ++r) {
                const int rw = w * 32 + mt * 16 + (lane >> 4) * 4 + r;
                smem[rw * 72 + col] = f2bf(acc[mt][nt][r]);
            }
        }
    __syncthreads();
#pragma unroll
    for (int it = 0; it < 4; ++it) {
        const int j = it * 256 + tid;       // 0..1023 chunks of 8
        const int row = j >> 3, c8 = (j & 7) * 8;
        const int m = m0 + row;
        const int b = m >> 11, c = m & (C_ - 1);
        *(u16x8*)&Out[(((size_t)(b * H_ + h) * C_ + c) << 6) + c8] =
            *(const u16x8*)&smem[row * 72 + c8];
    }
}

// ---------------------------------------------------------------------------
// GEMM 2 (MFMA bf16), 128x64 tiles -> 16x32 = 512 blocks (2.0/CU).
// united (4096x512) @ Wu^T-rows (1024x512) + bu -> new_out fp32
// ---------------------------------------------------------------------------
__global__ __launch_bounds__(256) void gemm_out_kernel(
    const uint16_t* __restrict__ U, const uint16_t* __restrict__ Wut,
    const float* __restrict__ bu, float* __restrict__ out)
{
    const int K = HD_;                      // 512
    const int m0 = blockIdx.y * 128;
    const int n0 = blockIdx.x * 64;         // N=1024

    __shared__ __align__(16) uint16_t As[128 * 32];
    __shared__ __align__(16) uint16_t Bs[64 * 32];

    const int tid = threadIdx.x;
    const int w = tid >> 6, lane = tid & 63;

    f32x4 acc[2][4] = {};

    const uint16_t* gP[3];
    uint16_t* lP[3];
#pragma unroll
    for (int j = 0; j < 3; ++j) {
        const int ci = w * 3 + j;
        const int ko = (lane & 3) * 8;
        if (ci < 8) {
            gP[j] = U + (size_t)(m0 + ci * 16 + (lane >> 2)) * K + ko;
            lP[j] = &As[ci * 512];
        } else {
            const int cb = ci - 8;
            gP[j] = Wut + (size_t)(n0 + cb * 16 + (lane >> 2)) * K + ko;
            lP[j] = &Bs[cb * 512];
        }
    }

    const int fr = lane & 15;
    const int fk = (lane >> 4) * 8;

    for (int k0 = 0; k0 < K; k0 += 32) {
        __syncthreads();
        gload16(gP[0] + k0, lP[0]);
        gload16(gP[1] + k0, lP[1]);
        gload16(gP[2] + k0, lP[2]);
        __syncthreads();
        bf16x8 af[2], bf[4];
#pragma unroll
        for (int mt = 0; mt < 2; ++mt)
            af[mt] = *(const bf16x8*)&As[(w * 32 + mt * 16 + fr) * 32 + fk];
#pragma unroll
        for (int nt = 0; nt < 4; ++nt)
            bf[nt] = *(const bf16x8*)&Bs[(nt * 16 + fr) * 32 + fk];
#pragma unroll
        for (int mt = 0; mt < 2; ++mt)
#pragma unroll
            for (int nt = 0; nt < 4; ++nt)
                acc[mt][nt] = __builtin_amdgcn_mfma_f32_16x16x32_bf16(
                    af[mt], bf[nt], acc[mt][nt], 0, 0, 0);
    }

#pragma unroll
    for (int mt = 0; mt < 2; ++mt) {
#pragma unroll
        for (int nt = 0; nt < 4; ++nt) {
            const int n = n0 + nt * 16 + fr;
            const float bias = bu[n];
#pragma unroll
            for (int r = 0; r < 4; ++r) {
                const int m = m0 + w * 32 + mt * 16 + (lane >> 4) * 4 + r;
                out[(size_t)m * E_ + n] = acc[mt][nt][r] + bias;
            }
        }
    }
}

// ---------------------------------------------------------------------------
// attention core.  One wave per (b,h,c) row.  The dense attentions matrix is
// zero-filled by hipMemsetAsync (fill engine runs at 81% HBM peak); here we
// only store the <=16 merged non-zero weights per row with plain dword
// stores (rows own disjoint 8KB regions; exactly one lane per distinct idx
// stores the duplicate-merged sum -> no atomics, no LDS, no barriers).
// ---------------------------------------------------------------------------
__global__ __launch_bounds__(256) void attn_kernel(
    const float* __restrict__ means, const float* __restrict__ sigmas,
    const float* __restrict__ values, const float* __restrict__ S,
    const uint16_t* __restrict__ Qt, const uint16_t* __restrict__ Kt,
    const uint16_t* __restrict__ Vt, uint16_t* __restrict__ united,
    float* __restrict__ attn)
{
    const int w = threadIdx.x >> 6;
    const int lane = threadIdx.x & 63;
    const int row = blockIdx.x * 4 + w;
    const int bh = row >> 11;
    const int c = row & (C_ - 1);
    const int b = bh >> 3;
    const int h = bh & 7;

    const float* mrow = means + (size_t)row * 8;
    const float4 ma = *(const float4*)(mrow);
    const float4 mb = *(const float4*)(mrow + 4);
    const float mm[8] = {ma.x, ma.y, ma.z, ma.w, mb.x, mb.y, mb.z, mb.w};

    int idx[16];
#pragma unroll
    for (int j = 0; j < 8; ++j) {
        int i0 = (int)floorf(mm[j]);
        i0 = min(max(i0, 0), C_ - 1);
        idx[2 * j] = i0;
        idx[2 * j + 1] = min(i0 + 1, C_ - 1);
    }

    // ---- per-point weights on lanes 0..15 ----
    const int lp = lane & 15;
    int myidx = 0;
#pragma unroll
    for (int q = 0; q < 16; ++q)
        if (q == lp) myidx = idx[q];
    float wp = 0.0f;
    if (lane < 16) {
        bool dup = false;
#pragma unroll
        for (int q = 0; q < 15; ++q)
            dup = dup || ((q < lane) && (idx[q] == myidx));
        if (!dup) {
            const float* srow = sigmas + (size_t)row * 8;
            const float* vrow = values + (size_t)row * 8;
            const float4 sa = *(const float4*)(srow);
            const float4 sb = *(const float4*)(srow + 4);
            const float4 va = *(const float4*)(vrow);
            const float4 vb = *(const float4*)(vrow + 4);
            const float sg[8] = {sa.x, sa.y, sa.z, sa.w, sb.x, sb.y, sb.z, sb.w};
            const float vl[8] = {va.x, va.y, va.z, va.w, vb.x, vb.y, vb.z, vb.w};
            const float* Sp = S + bh * 128 + lane * 8;
            const float4 Sa = *(const float4*)(Sp);
            const float4 Sb = *(const float4*)(Sp + 4);
            const float Sv[8] = {Sa.x, Sa.y, Sa.z, Sa.w, Sb.x, Sb.y, Sb.z, Sb.w};
            const float fi = (float)myidx;
#pragma unroll
            for (int kk = 0; kk < 8; ++kk) {
                const float t = (fi - mm[kk]) / sg[kk];
                const float e = expf(-0.5f * t * t);
                wp = fmaf(vl[kk], e / (Sv[kk] + 1e-8f), wp);
            }
        }
    }

    // ---- dots in (p,g) layout: p = point, g covers dims [g*16, g*16+16) ----
    const int p = lane >> 2, g = lane & 3;
    int kidx = 0;
#pragma unroll
    for (int q = 0; q < 16; ++q)
        if (q == p) kidx = idx[q];

    const uint16_t* Qrow = Qt + ((size_t)row << 6);
    const uint16_t* Krow = Kt + ((((size_t)bh << 11) + kidx) << 6);
    const u16x8 qa = *(const u16x8*)(Qrow + g * 16);
    const u16x8 qb = *(const u16x8*)(Qrow + g * 16 + 8);
    const u16x8 ka = *(const u16x8*)(Krow + g * 16);
    const u16x8 kb = *(const u16x8*)(Krow + g * 16 + 8);
    float dot = 0.0f;
#pragma unroll
    for (int j = 0; j < 8; ++j) {
        dot = fmaf(bf2f(qa[j]), bf2f(ka[j]), dot);
        dot = fmaf(bf2f(qb[j]), bf2f(kb[j]), dot);
    }
    dot += __shfl_xor(dot, 1);
    dot += __shfl_xor(dot, 2);

    const float wvp = __shfl(wp, p);
    const float logit = wvp * dot;

    float mx = logit;
#pragma unroll
    for (int off = 4; off < 64; off <<= 1)
        mx = fmaxf(mx, __shfl_xor(mx, off));
    const float e = expf(logit - mx);
    float se = e;
#pragma unroll
    for (int off = 4; off < 64; off <<= 1)
        se += __shfl_xor(se, off);
    const float sm = e / se;

    float smv[16];
#pragma unroll
    for (int q = 0; q < 16; ++q)
        smv[q] = __shfl(sm, q * 4);

    // ---- V combine (lane = d) ----
    const uint16_t* Vbh = Vt + ((size_t)bh << 17);
    float acc = 0.0f;
#pragma unroll
    for (int q = 0; q < 16; ++q)
        acc = fmaf(bf2f(Vbh[((size_t)idx[q] << 6) + lane]), smv[q], acc);
    united[((size_t)(b * C_ + c)) * HD_ + h * 64 + lane] = f2bf(acc);

    // ---- attentions row: merged sparse store (background zeros via memset) ----
    float* arow = attn + ((size_t)row << 11);
    if (lane < 16) {
        bool first = true;
        float sum = 0.0f;
#pragma unroll
        for (int q = 0; q < 16; ++q) {
            if (idx[q] == myidx) {
                if (q < lane) first = false;
                sum += smv[q];
            }
        }
        if (first) arow[myidx] = sum;
    }
}

// ---------------------------------------------------------------------------
extern "C" void kernel_launch(void* const* d_in, const int* in_sizes, int n_in,
                              void* d_out, int out_size, void* d_ws,
                              size_t ws_size, hipStream_t stream) {
    const float* x      = (const float*)d_in[0];
    const float* means  = (const float*)d_in[2];
    const float* sigmas = (const float*)d_in[3];
    const float* values = (const float*)d_in[4];
    const float* Wk     = (const float*)d_in[5];
    const float* Wq     = (const float*)d_in[6];
    const float* Wv     = (const float*)d_in[7];
    const float* Wu     = (const float*)d_in[8];
    const float* bu     = (const float*)d_in[9];

    float* out  = (float*)d_out;
    float* attn = out + (size_t)M_ * E_;

    uint16_t* wsp = (uint16_t*)d_ws;
    uint16_t* xb     = wsp;                              // 4194304
    uint16_t* Wall   = xb + 4194304;                     // 1572864 (1536x1024)
    uint16_t* Wut    = Wall + 1572864;                   // 524288
    uint16_t* Qt     = Wut + 524288;                     // 2097152
    uint16_t* Kt     = Qt + 2097152;
    uint16_t* Vt     = Kt + 2097152;
    uint16_t* united = Vt + 2097152;                     // 2097152
    float*    S      = (float*)(united + 2097152);       // 2048 floats

    (void)hipMemsetAsync(S, 0, 2048 * sizeof(float), stream);
    // zero the dense attentions output on the fill engine (81% of HBM peak
    // measured); attn_kernel then stores only the <=16 non-zeros per row.
    (void)hipMemsetAsync(attn, 0,
                         (size_t)B_ * H_ * C_ * C_ * sizeof(float), stream);

    prep_kernel<<<4224, 256, 0, stream>>>(
        x, Wq, Wk, Wv, Wu, means, sigmas, xb, Wall, Wut, S);
    gemm_qkv_kernel<<<dim3(24, 32), 256, 0, stream>>>(xb, Wall, Qt, Kt, Vt);
    attn_kernel<<<ROWS_ / 4, 256, 0, stream>>>(
        means, sigmas, values, S, Qt, Kt, Vt, united, attn);
    gemm_out_kernel<<<dim3(16, 32), 256, 0, stream>>>(united, Wut, bu, out);
}

// Round 2
// 387.287 us; speedup vs baseline: 1.1623x; 1.1623x over previous
//
#include <hip/hip_runtime.h>
#include <math.h>
#include <stdint.h>

#define B_ 2
#define H_ 8
#define C_ 2048
#define E_ 1024
#define D_ 64
#define KP_ 8
#define P_ 16
#define HD_ 512              // H*D
#define ROWS_ 32768          // B*H*C
#define M_ 4096              // B*C

typedef __bf16 bf16x8 __attribute__((ext_vector_type(8)));
typedef float f32x4 __attribute__((ext_vector_type(4)));
typedef uint16_t u16x8 __attribute__((ext_vector_type(8)));

__device__ inline uint16_t f2bf(float f) {
    union { float f; uint32_t u; } v; v.f = f;
    uint32_t u = v.u + 0x7FFF + ((v.u >> 16) & 1);   // RNE
    return (uint16_t)(u >> 16);
}
__device__ inline float bf2f(uint16_t h) {
    union { uint32_t u; float f; } v; v.u = ((uint32_t)h) << 16;
    return v.f;
}

// async global->LDS, 16B per lane; LDS dest = wave-uniform base + lane*16
__device__ inline void gload16(const uint16_t* g, uint16_t* l) {
    __builtin_amdgcn_global_load_lds(
        (const __attribute__((address_space(1))) void*)g,
        (__attribute__((address_space(3))) void*)l, 16, 0, 0);
}

// ---------------------------------------------------------------------------
// prep kernel: x-convert, weight transpose-convert, density context-sums.
//   blocks [0, 2048)      : convert x (fp32 -> bf16), 8 elem/thread
//   blocks [2048, 4096)   : transpose-convert one 32x32 weight tile
//   blocks [4096, 4224)   : density sums (one thread per (b,h,c) row)
//     butterfly recursive-halving reduce (126 shfl+add vs 768 before),
//     block-level LDS combine -> 128 global atomics per block (4x fewer).
// ---------------------------------------------------------------------------
__global__ __launch_bounds__(256) void prep_kernel(
    const float* __restrict__ x,
    const float* __restrict__ Wq, const float* __restrict__ Wk,
    const float* __restrict__ Wv, const float* __restrict__ Wu,
    const float* __restrict__ means, const float* __restrict__ sigmas,
    uint16_t* __restrict__ xb, uint16_t* __restrict__ Wall,
    uint16_t* __restrict__ Wut, float* __restrict__ S)
{
    const int bx = blockIdx.x;
    if (bx < 2048) {
        const int i = (bx * 256 + threadIdx.x) * 8;
        const float4 a = *(const float4*)(x + i);
        const float4 b = *(const float4*)(x + i + 4);
        u16x8 o;
        o[0] = f2bf(a.x); o[1] = f2bf(a.y); o[2] = f2bf(a.z); o[3] = f2bf(a.w);
        o[4] = f2bf(b.x); o[5] = f2bf(b.y); o[6] = f2bf(b.z); o[7] = f2bf(b.w);
        *(u16x8*)(xb + i) = o;
        return;
    }
    if (bx < 4096) {
        const int t = bx - 2048;
        const int z = t >> 9;
        const float* in; uint16_t* out; int R, Cc; float scale;
        if (z == 0)      { in = Wq; out = Wall;               R = E_;  Cc = HD_; scale = 0.125f; }
        else if (z == 1) { in = Wk; out = Wall + 512 * 1024;  R = E_;  Cc = HD_; scale = 0.125f; }
        else if (z == 2) { in = Wv; out = Wall + 1024 * 1024; R = E_;  Cc = HD_; scale = 1.0f; }
        else             { in = Wu; out = Wut;                R = HD_; Cc = E_;  scale = 1.0f; }
        const int tiles_x = Cc >> 5;
        const int ti = t & 511;
        const int tx = ti % tiles_x;
        const int ty = ti / tiles_x;
        const int r0 = ty * 32, c0 = tx * 32;
        __shared__ float tbuf[32][33];
        const int lx = threadIdx.x & 31, ly = threadIdx.x >> 5;
#pragma unroll
        for (int i = 0; i < 4; ++i)
            tbuf[ly * 4 + i][lx] = in[(size_t)(r0 + ly * 4 + i) * Cc + c0 + lx];
        __syncthreads();
#pragma unroll
        for (int i = 0; i < 4; ++i)
            out[(size_t)(c0 + ly * 4 + i) * R + r0 + lx] =
                f2bf(tbuf[lx][ly * 4 + i] * scale);
        return;
    }
    // ---- density sums ----
    const int row = (bx - 4096) * 256 + threadIdx.x;
    const int lane = threadIdx.x & 63;
    const int bh = row >> 11;          // constant per block (256 rows/block)

    __shared__ float Sacc[128];
    if (threadIdx.x < 128) Sacc[threadIdx.x] = 0.0f;
    __syncthreads();

    const float* mrow = means + (size_t)row * 8;
    const float* srow = sigmas + (size_t)row * 8;
    const float4 ma = *(const float4*)(mrow);
    const float4 mb = *(const float4*)(mrow + 4);
    const float4 sa = *(const float4*)(srow);
    const float4 sb = *(const float4*)(srow + 4);
    const float mm[8] = {ma.x, ma.y, ma.z, ma.w, mb.x, mb.y, mb.z, mb.w};
    const float sg[8] = {sa.x, sa.y, sa.z, sa.w, sb.x, sb.y, sb.z, sb.w};

    int idx[16];
#pragma unroll
    for (int j = 0; j < 8; ++j) {
        int i0 = (int)floorf(mm[j]);
        i0 = min(max(i0, 0), C_ - 1);
        idx[2 * j] = i0;
        idx[2 * j + 1] = min(i0 + 1, C_ - 1);
    }
    unsigned dupm = 0;
#pragma unroll
    for (int p = 1; p < 16; ++p) {
        bool d = false;
#pragma unroll
        for (int q = 0; q < 15; ++q)
            if (q < p) d = d || (idx[q] == idx[p]);
        if (d) dupm |= (1u << p);
    }

    // lane's final slot after the 6-stage butterfly is bitrev6(lane)
    const int rev = ((lane & 1) << 5) | ((lane & 2) << 3) | ((lane & 4) << 1) |
                    ((lane & 8) >> 1) | ((lane & 16) >> 3) | ((lane & 32) >> 5);

#pragma unroll
    for (int ph = 0; ph < 2; ++ph) {
        float a[64];
#pragma unroll
        for (int j = 0; j < 64; ++j) {
            const int p = ph * 8 + (j >> 3);
            const int kk = j & 7;
            const float fi = (float)idx[p];
            const float t = (fi - mm[kk]) / sg[kk];
            const float e = expf(-0.5f * t * t);
            a[j] = ((dupm >> p) & 1u) ? 0.0f : e;
        }
        // recursive halving: stage b keeps 32>>b values; lane keeps the
        // (lane>>b)&1 half of its current range, exchanges the other half.
#pragma unroll
        for (int b = 0; b < 6; ++b) {
            const int n = 32 >> b;
            const bool hi = (lane >> b) & 1;
#pragma unroll
            for (int j = 0; j < n; ++j) {
                float send = hi ? a[j] : a[j + n];
                float recv = __shfl_xor(send, 1 << b);
                a[j] = (hi ? a[j + n] : a[j]) + recv;
            }
        }
        atomicAdd(&Sacc[ph * 64 + rev], a[0]);
    }
    __syncthreads();
    if (threadIdx.x < 128)
        atomicAdd(&S[bh * 128 + threadIdx.x], Sacc[threadIdx.x]);
}

// ---------------------------------------------------------------------------
// Fused QKV GEMM (MFMA bf16), 128x64 tiles, BK=64 (two linear 32-col slabs
// per barrier pair -> 16 barrier pairs instead of 32, 16 MFMA per drain).
// N-tile = 64 = exactly one head: epilogue rows are 128B-contiguous in Out.
// ---------------------------------------------------------------------------
__global__ __launch_bounds__(256) void gemm_qkv_kernel(
    const uint16_t* __restrict__ xb, const uint16_t* __restrict__ Wall,
    uint16_t* __restrict__ Qt, uint16_t* __restrict__ Kt,
    uint16_t* __restrict__ Vt)
{
    const int K = E_;                       // 1024
    const int m0 = blockIdx.y * 128;
    const int n0 = blockIdx.x * 64;         // 0..1535
    const int z = n0 >> 9;
    uint16_t* __restrict__ Out = (z == 0) ? Qt : (z == 1) ? Kt : Vt;
    const int h = (n0 & 511) >> 6;          // single head per block

    // As0[0,4096) Bs0[4096,6144) As1[6144,10240) Bs1[10240,12288)
    // epilogue: 128 x 72-stride bf16 tile in smem[0..9216)
    __shared__ __align__(16) uint16_t smem[12288];

    const int tid = threadIdx.x;
    const int w = tid >> 6, lane = tid & 63;

    f32x4 acc[2][4] = {};

    // staging: 12 chunks of 16 rows x 32 cols; wave w: chunks 3w..3w+2
    const uint16_t* gP[3];
    uint16_t* lP[3];
#pragma unroll
    for (int j = 0; j < 3; ++j) {
        const int ci = w * 3 + j;
        const int rr = (ci & 7) * 16 + (lane >> 2);   // works for both halves
        const int ko = (lane & 3) * 8;
        if (ci < 8) {
            gP[j] = xb + (size_t)(m0 + rr) * K + ko;
            lP[j] = &smem[ci * 512];
        } else {
            const int cb = ci - 8;
            gP[j] = Wall + (size_t)(n0 + cb * 16 + (lane >> 2)) * K + ko;
            lP[j] = &smem[4096 + cb * 512];
        }
    }

    const int fr = lane & 15;
    const int fk = (lane >> 4) * 8;

    for (int k0 = 0; k0 < K; k0 += 64) {
        __syncthreads();
#pragma unroll
        for (int j = 0; j < 3; ++j) {
            gload16(gP[j] + k0, lP[j]);
            gload16(gP[j] + k0 + 32, lP[j] + 6144);
        }
        __syncthreads();
#pragma unroll
        for (int half = 0; half < 2; ++half) {
            const int base = half * 6144;
            bf16x8 af[2], bf[4];
#pragma unroll
            for (int mt = 0; mt < 2; ++mt)
                af[mt] = *(const bf16x8*)&smem[base + (w * 32 + mt * 16 + fr) * 32 + fk];
#pragma unroll
            for (int nt = 0; nt < 4; ++nt)
                bf[nt] = *(const bf16x8*)&smem[base + 4096 + (nt * 16 + fr) * 32 + fk];
#pragma unroll
            for (int mt = 0; mt < 2; ++mt)
#pragma unroll
                for (int nt = 0; nt < 4; ++nt)
                    acc[mt][nt] = __builtin_amdgcn_mfma_f32_16x16x32_bf16(
                        af[mt], bf[nt], acc[mt][nt], 0, 0, 0);
        }
    }

    // ---- epilogue: stage 128x64 bf16 tile (stride 72), stream coalesced ----
    __syncthreads();
#pragma unroll
    for (int mt = 0; mt < 2; ++mt)
#pragma unroll
        for (int nt = 0; nt < 4; ++nt) {
            const int col = nt * 16 + fr;
#pragma unroll
            for (int r = 0; r < 4; ++r) {
                const int rw = w * 32 + mt * 16 + (lane >> 4) * 4 + r;
                smem[rw * 72 + col] = f2bf(acc[mt][nt][r]);
            }
        }
    __syncthreads();
#pragma unroll
    for (int it = 0; it < 4; ++it) {
        const int j = it * 256 + tid;       // 0..1023 chunks of 8
        const int row = j >> 3, c8 = (j & 7) * 8;
        const int m = m0 + row;
        const int b = m >> 11, c = m & (C_ - 1);
        *(u16x8*)&Out[(((size_t)(b * H_ + h) * C_ + c) << 6) + c8] =
            *(const u16x8*)&smem[row * 72 + c8];
    }
}

// ---------------------------------------------------------------------------
// GEMM 2 (MFMA bf16), 128x64 tiles, BK=64 -> 8 barrier pairs (K=512).
// united (4096x512) @ Wu^T-rows (1024x512) + bu -> new_out fp32
// ---------------------------------------------------------------------------
__global__ __launch_bounds__(256) void gemm_out_kernel(
    const uint16_t* __restrict__ U, const uint16_t* __restrict__ Wut,
    const float* __restrict__ bu, float* __restrict__ out)
{
    const int K = HD_;                      // 512
    const int m0 = blockIdx.y * 128;
    const int n0 = blockIdx.x * 64;         // N=1024

    __shared__ __align__(16) uint16_t smem[12288];

    const int tid = threadIdx.x;
    const int w = tid >> 6, lane = tid & 63;

    f32x4 acc[2][4] = {};

    const uint16_t* gP[3];
    uint16_t* lP[3];
#pragma unroll
    for (int j = 0; j < 3; ++j) {
        const int ci = w * 3 + j;
        const int ko = (lane & 3) * 8;
        if (ci < 8) {
            gP[j] = U + (size_t)(m0 + ci * 16 + (lane >> 2)) * K + ko;
            lP[j] = &smem[ci * 512];
        } else {
            const int cb = ci - 8;
            gP[j] = Wut + (size_t)(n0 + cb * 16 + (lane >> 2)) * K + ko;
            lP[j] = &smem[4096 + cb * 512];
        }
    }

    const int fr = lane & 15;
    const int fk = (lane >> 4) * 8;

    for (int k0 = 0; k0 < K; k0 += 64) {
        __syncthreads();
#pragma unroll
        for (int j = 0; j < 3; ++j) {
            gload16(gP[j] + k0, lP[j]);
            gload16(gP[j] + k0 + 32, lP[j] + 6144);
        }
        __syncthreads();
#pragma unroll
        for (int half = 0; half < 2; ++half) {
            const int base = half * 6144;
            bf16x8 af[2], bf[4];
#pragma unroll
            for (int mt = 0; mt < 2; ++mt)
                af[mt] = *(const bf16x8*)&smem[base + (w * 32 + mt * 16 + fr) * 32 + fk];
#pragma unroll
            for (int nt = 0; nt < 4; ++nt)
                bf[nt] = *(const bf16x8*)&smem[base + 4096 + (nt * 16 + fr) * 32 + fk];
#pragma unroll
            for (int mt = 0; mt < 2; ++mt)
#pragma unroll
                for (int nt = 0; nt < 4; ++nt)
                    acc[mt][nt] = __builtin_amdgcn_mfma_f32_16x16x32_bf16(
                        af[mt], bf[nt], acc[mt][nt], 0, 0, 0);
        }
    }

#pragma unroll
    for (int mt = 0; mt < 2; ++mt) {
#pragma unroll
        for (int nt = 0; nt < 4; ++nt) {
            const int n = n0 + nt * 16 + fr;
            const float bias = bu[n];
#pragma unroll
            for (int r = 0; r < 4; ++r) {
                const int m = m0 + w * 32 + mt * 16 + (lane >> 4) * 4 + r;
                out[(size_t)m * E_ + n] = acc[mt][nt][r] + bias;
            }
        }
    }
}

// ---------------------------------------------------------------------------
// attention core.  One wave per (b,h,c) row; fused dense-row write via LDS
// (nontemporal stream ~ write roofline; sparse+memset was measured WORSE:
// +134MB partial-line RMW traffic + serialized fill).
// Softmax weights now wave-parallel on the (p = lane>>2, g = lane&3) layout:
// 2 expf/lane + 2 shfl_xor instead of 8 serial expf on 16 divergent lanes.
// ---------------------------------------------------------------------------
__global__ __launch_bounds__(256) void attn_kernel(
    const float* __restrict__ means, const float* __restrict__ sigmas,
    const float* __restrict__ values, const float* __restrict__ S,
    const uint16_t* __restrict__ Qt, const uint16_t* __restrict__ Kt,
    const uint16_t* __restrict__ Vt, uint16_t* __restrict__ united,
    float* __restrict__ attn)
{
    __shared__ float rowbuf[4][2048];
    const int w = threadIdx.x >> 6;
    const int lane = threadIdx.x & 63;
    const int row = blockIdx.x * 4 + w;
    const int bh = row >> 11;
    const int c = row & (C_ - 1);
    const int b = bh >> 3;
    const int h = bh & 7;

    const float* mrow = means + (size_t)row * 8;
    const float4 ma = *(const float4*)(mrow);
    const float4 mb = *(const float4*)(mrow + 4);
    const float mm[8] = {ma.x, ma.y, ma.z, ma.w, mb.x, mb.y, mb.z, mb.w};

    int idx[16];
#pragma unroll
    for (int j = 0; j < 8; ++j) {
        int i0 = (int)floorf(mm[j]);
        i0 = min(max(i0, 0), C_ - 1);
        idx[2 * j] = i0;
        idx[2 * j + 1] = min(i0 + 1, C_ - 1);
    }

    // ---- (p,g) layout: p = point (lane>>2), g = quarter (lane&3) ----
    const int p = lane >> 2, g = lane & 3;
    int kidx = 0;
#pragma unroll
    for (int q = 0; q < 16; ++q)
        if (q == p) kidx = idx[q];

    // duplicate-point check for own p (wave-uniform idx[] in registers)
    bool dup = false;
#pragma unroll
    for (int q = 0; q < 15; ++q)
        dup = dup || ((q < p) && (idx[q] == kidx));

    // ---- per-point weight, parallel over (p, kk): lane handles kk=g,g+4 ----
    float mA = 0.f, mB = 0.f;
#pragma unroll
    for (int q = 0; q < 4; ++q)
        if (q == g) { mA = mm[q]; mB = mm[q + 4]; }
    const float* srow = sigmas + (size_t)row * 8;
    const float* vrow = values + (size_t)row * 8;
    const float* Sp = S + bh * 128 + p * 8;
    const float sgA = srow[g], sgB = srow[g + 4];
    const float vlA = vrow[g], vlB = vrow[g + 4];
    const float SvA = Sp[g],   SvB = Sp[g + 4];
    const float fi = (float)kidx;
    const float tA = (fi - mA) / sgA;
    const float tB = (fi - mB) / sgB;
    const float eA = expf(-0.5f * tA * tA);
    const float eB = expf(-0.5f * tB * tB);
    float wp = dup ? 0.0f
                   : fmaf(vlA, eA / (SvA + 1e-8f), vlB * eB / (SvB + 1e-8f));
    wp += __shfl_xor(wp, 1);
    wp += __shfl_xor(wp, 2);          // wp == wvp, replicated in 4-lane group

    // ---- Q.K dot: lane covers dims [g*16, g*16+16) of point p ----
    const uint16_t* Qrow = Qt + ((size_t)row << 6);
    const uint16_t* Krow = Kt + ((((size_t)bh << 11) + kidx) << 6);
    const u16x8 qa = *(const u16x8*)(Qrow + g * 16);
    const u16x8 qb = *(const u16x8*)(Qrow + g * 16 + 8);
    const u16x8 ka = *(const u16x8*)(Krow + g * 16);
    const u16x8 kb = *(const u16x8*)(Krow + g * 16 + 8);
    float dot = 0.0f;
#pragma unroll
    for (int j = 0; j < 8; ++j) {
        dot = fmaf(bf2f(qa[j]), bf2f(ka[j]), dot);
        dot = fmaf(bf2f(qb[j]), bf2f(kb[j]), dot);
    }
    dot += __shfl_xor(dot, 1);
    dot += __shfl_xor(dot, 2);

    const float logit = wp * dot;

    float mx = logit;
#pragma unroll
    for (int off = 4; off < 64; off <<= 1)
        mx = fmaxf(mx, __shfl_xor(mx, off));
    const float e = expf(logit - mx);
    float se = e;
#pragma unroll
    for (int off = 4; off < 64; off <<= 1)
        se += __shfl_xor(se, off);
    const float sm = e / se;

    float smv[16];
#pragma unroll
    for (int q = 0; q < 16; ++q)
        smv[q] = __shfl(sm, q * 4);

    // ---- V combine (lane = d) ----
    const uint16_t* Vbh = Vt + ((size_t)bh << 17);
    float acc = 0.0f;
#pragma unroll
    for (int q = 0; q < 16; ++q)
        acc = fmaf(bf2f(Vbh[((size_t)idx[q] << 6) + lane]), smv[q], acc);
    united[((size_t)(b * C_ + c)) * HD_ + h * 64 + lane] = f2bf(acc);

    // ---- attentions row: zero LDS, scatter-add, nontemporal stream out ----
    const f32x4 z4 = {0.f, 0.f, 0.f, 0.f};
#pragma unroll
    for (int j = 0; j < 8; ++j)
        *(f32x4*)&rowbuf[w][(j * 64 + lane) * 4] = z4;
    __syncthreads();
    if (g == 0) atomicAdd(&rowbuf[w][kidx], sm);   // one lane per point p
    __syncthreads();
    float* arow = attn + ((size_t)row << 11);
#pragma unroll
    for (int j = 0; j < 8; ++j) {
        const int o = (j * 64 + lane) * 4;
        __builtin_nontemporal_store(*(const f32x4*)&rowbuf[w][o], (f32x4*)&arow[o]);
    }
}

// ---------------------------------------------------------------------------
extern "C" void kernel_launch(void* const* d_in, const int* in_sizes, int n_in,
                              void* d_out, int out_size, void* d_ws,
                              size_t ws_size, hipStream_t stream) {
    const float* x      = (const float*)d_in[0];
    const float* means  = (const float*)d_in[2];
    const float* sigmas = (const float*)d_in[3];
    const float* values = (const float*)d_in[4];
    const float* Wk     = (const float*)d_in[5];
    const float* Wq     = (const float*)d_in[6];
    const float* Wv     = (const float*)d_in[7];
    const float* Wu     = (const float*)d_in[8];
    const float* bu     = (const float*)d_in[9];

    float* out  = (float*)d_out;
    float* attn = out + (size_t)M_ * E_;

    uint16_t* wsp = (uint16_t*)d_ws;
    uint16_t* xb     = wsp;                              // 4194304
    uint16_t* Wall   = xb + 4194304;                     // 1572864 (1536x1024)
    uint16_t* Wut    = Wall + 1572864;                   // 524288
    uint16_t* Qt     = Wut + 524288;                     // 2097152
    uint16_t* Kt     = Qt + 2097152;
    uint16_t* Vt     = Kt + 2097152;
    uint16_t* united = Vt + 2097152;                     // 2097152
    float*    S      = (float*)(united + 2097152);       // 2048 floats

    (void)hipMemsetAsync(S, 0, 2048 * sizeof(float), stream);

    prep_kernel<<<4224, 256, 0, stream>>>(
        x, Wq, Wk, Wv, Wu, means, sigmas, xb, Wall, Wut, S);
    gemm_qkv_kernel<<<dim3(24, 32), 256, 0, stream>>>(xb, Wall, Qt, Kt, Vt);
    attn_kernel<<<ROWS_ / 4, 256, 0, stream>>>(
        means, sigmas, values, S, Qt, Kt, Vt, united, attn);
    gemm_out_kernel<<<dim3(16, 32), 256, 0, stream>>>(united, Wut, bu, out);
}

// Round 5
// 385.027 us; speedup vs baseline: 1.1691x; 1.0059x over previous
//
#include <hip/hip_runtime.h>
#include <math.h>
#include <stdint.h>

#define B_ 2
#define H_ 8
#define C_ 2048
#define E_ 1024
#define D_ 64
#define KP_ 8
#define P_ 16
#define HD_ 512              // H*D
#define ROWS_ 32768          // B*H*C
#define M_ 4096              // B*C

typedef __bf16 bf16x8 __attribute__((ext_vector_type(8)));
typedef float f32x4 __attribute__((ext_vector_type(4)));
typedef uint16_t u16x8 __attribute__((ext_vector_type(8)));

__device__ inline uint16_t f2bf(float f) {
    union { float f; uint32_t u; } v; v.f = f;
    uint32_t u = v.u + 0x7FFF + ((v.u >> 16) & 1);   // RNE
    return (uint16_t)(u >> 16);
}
__device__ inline float bf2f(uint16_t h) {
    union { uint32_t u; float f; } v; v.u = ((uint32_t)h) << 16;
    return v.f;
}

// async global->LDS, 16B per lane; LDS dest = wave-uniform base + lane*16
__device__ inline void gload16(const uint16_t* g, uint16_t* l) {
    __builtin_amdgcn_global_load_lds(
        (const __attribute__((address_space(1))) void*)g,
        (__attribute__((address_space(3))) void*)l, 16, 0, 0);
}

// ---------------------------------------------------------------------------
// prep kernel: x-convert, weight transpose-convert, density context-sums.
//   blocks [0, 2048)      : convert x (fp32 -> bf16), 8 elem/thread
//   blocks [2048, 4096)   : transpose-convert one 32x32 weight tile
//   blocks [4096, 4224)   : density sums (one thread per (b,h,c) row)
//     butterfly recursive-halving reduce, block-level LDS combine.
// ---------------------------------------------------------------------------
__global__ __launch_bounds__(256) void prep_kernel(
    const float* __restrict__ x,
    const float* __restrict__ Wq, const float* __restrict__ Wk,
    const float* __restrict__ Wv, const float* __restrict__ Wu,
    const float* __restrict__ means, const float* __restrict__ sigmas,
    uint16_t* __restrict__ xb, uint16_t* __restrict__ Wall,
    uint16_t* __restrict__ Wut, float* __restrict__ S)
{
    const int bx = blockIdx.x;
    if (bx < 2048) {
        const int i = (bx * 256 + threadIdx.x) * 8;
        const float4 a = *(const float4*)(x + i);
        const float4 b = *(const float4*)(x + i + 4);
        u16x8 o;
        o[0] = f2bf(a.x); o[1] = f2bf(a.y); o[2] = f2bf(a.z); o[3] = f2bf(a.w);
        o[4] = f2bf(b.x); o[5] = f2bf(b.y); o[6] = f2bf(b.z); o[7] = f2bf(b.w);
        *(u16x8*)(xb + i) = o;
        return;
    }
    if (bx < 4096) {
        const int t = bx - 2048;
        const int z = t >> 9;
        const float* in; uint16_t* out; int R, Cc; float scale;
        if (z == 0)      { in = Wq; out = Wall;               R = E_;  Cc = HD_; scale = 0.125f; }
        else if (z == 1) { in = Wk; out = Wall + 512 * 1024;  R = E_;  Cc = HD_; scale = 0.125f; }
        else if (z == 2) { in = Wv; out = Wall + 1024 * 1024; R = E_;  Cc = HD_; scale = 1.0f; }
        else             { in = Wu; out = Wut;                R = HD_; Cc = E_;  scale = 1.0f; }
        const int tiles_x = Cc >> 5;
        const int ti = t & 511;
        const int tx = ti % tiles_x;
        const int ty = ti / tiles_x;
        const int r0 = ty * 32, c0 = tx * 32;
        __shared__ float tbuf[32][33];
        const int lx = threadIdx.x & 31, ly = threadIdx.x >> 5;
#pragma unroll
        for (int i = 0; i < 4; ++i)
            tbuf[ly * 4 + i][lx] = in[(size_t)(r0 + ly * 4 + i) * Cc + c0 + lx];
        __syncthreads();
#pragma unroll
        for (int i = 0; i < 4; ++i)
            out[(size_t)(c0 + ly * 4 + i) * R + r0 + lx] =
                f2bf(tbuf[lx][ly * 4 + i] * scale);
        return;
    }
    // ---- density sums ----
    const int row = (bx - 4096) * 256 + threadIdx.x;
    const int lane = threadIdx.x & 63;
    const int bh = row >> 11;          // constant per block (256 rows/block)

    __shared__ float Sacc[128];
    if (threadIdx.x < 128) Sacc[threadIdx.x] = 0.0f;
    __syncthreads();

    const float* mrow = means + (size_t)row * 8;
    const float* srow = sigmas + (size_t)row * 8;
    const float4 ma = *(const float4*)(mrow);
    const float4 mb = *(const float4*)(mrow + 4);
    const float4 sa = *(const float4*)(srow);
    const float4 sb = *(const float4*)(srow + 4);
    const float mm[8] = {ma.x, ma.y, ma.z, ma.w, mb.x, mb.y, mb.z, mb.w};
    const float sg[8] = {sa.x, sa.y, sa.z, sa.w, sb.x, sb.y, sb.z, sb.w};

    int idx[16];
#pragma unroll
    for (int j = 0; j < 8; ++j) {
        int i0 = (int)floorf(mm[j]);
        i0 = min(max(i0, 0), C_ - 1);
        idx[2 * j] = i0;
        idx[2 * j + 1] = min(i0 + 1, C_ - 1);
    }
    unsigned dupm = 0;
#pragma unroll
    for (int p = 1; p < 16; ++p) {
        bool d = false;
#pragma unroll
        for (int q = 0; q < 15; ++q)
            if (q < p) d = d || (idx[q] == idx[p]);
        if (d) dupm |= (1u << p);
    }

    // lane's final slot after the 6-stage butterfly is bitrev6(lane)
    const int rev = ((lane & 1) << 5) | ((lane & 2) << 3) | ((lane & 4) << 1) |
                    ((lane & 8) >> 1) | ((lane & 16) >> 3) | ((lane & 32) >> 5);

#pragma unroll
    for (int ph = 0; ph < 2; ++ph) {
        float a[64];
#pragma unroll
        for (int j = 0; j < 64; ++j) {
            const int p = ph * 8 + (j >> 3);
            const int kk = j & 7;
            const float fi = (float)idx[p];
            const float t = (fi - mm[kk]) / sg[kk];
            const float e = expf(-0.5f * t * t);
            a[j] = ((dupm >> p) & 1u) ? 0.0f : e;
        }
        // recursive halving: stage b keeps 32>>b values; lane keeps the
        // (lane>>b)&1 half of its current range, exchanges the other half.
#pragma unroll
        for (int b = 0; b < 6; ++b) {
            const int n = 32 >> b;
            const bool hi = (lane >> b) & 1;
#pragma unroll
            for (int j = 0; j < n; ++j) {
                float send = hi ? a[j] : a[j + n];
                float recv = __shfl_xor(send, 1 << b);
                a[j] = (hi ? a[j + n] : a[j]) + recv;
            }
        }
        atomicAdd(&Sacc[ph * 64 + rev], a[0]);
    }
    __syncthreads();
    if (threadIdx.x < 128)
        atomicAdd(&S[bh * 128 + threadIdx.x], Sacc[threadIdx.x]);
}

// ---------------------------------------------------------------------------
// Fused QKV GEMM (MFMA bf16), 128x64 tiles, BK=64, DOUBLE-BUFFERED prefetch:
// stage(next buf) -> compute(cur) -> syncthreads (prefetch vmcnt drains under
// compute) -> flip.  One barrier per K-step; load latency hidden (T3 2-phase).
// N-tile = 64 = exactly one head: epilogue rows are 128B-contiguous in Out.
// ---------------------------------------------------------------------------
__global__ __launch_bounds__(256) void gemm_qkv_kernel(
    const uint16_t* __restrict__ xb, const uint16_t* __restrict__ Wall,
    uint16_t* __restrict__ Qt, uint16_t* __restrict__ Kt,
    uint16_t* __restrict__ Vt)
{
    const int K = E_;                       // 1024
    const int m0 = blockIdx.y * 128;
    const int n0 = blockIdx.x * 64;         // 0..1535
    const int z = n0 >> 9;
    uint16_t* __restrict__ Out = (z == 0) ? Qt : (z == 1) ? Kt : Vt;
    const int h = (n0 & 511) >> 6;          // single head per block

    // per buffer (12288 u16): A0[0,4096) B0[4096,6144) A1[6144,10240) B1[10240,12288)
    // epilogue reuses smem[0..9216) as 128 x 72-stride bf16 tile
    __shared__ __align__(16) uint16_t smem[24576];   // 48 KB, 3 blocks/CU

    const int tid = threadIdx.x;
    const int w = tid >> 6, lane = tid & 63;

    f32x4 acc[2][4] = {};

    // staging: 12 chunks of 16 rows x 32 cols; wave w: chunks 3w..3w+2
    const uint16_t* gP[3];
    uint16_t* lP[3];
#pragma unroll
    for (int j = 0; j < 3; ++j) {
        const int ci = w * 3 + j;
        const int rr = (ci & 7) * 16 + (lane >> 2);   // works for both halves
        const int ko = (lane & 3) * 8;
        if (ci < 8) {
            gP[j] = xb + (size_t)(m0 + rr) * K + ko;
            lP[j] = &smem[ci * 512];
        } else {
            const int cb = ci - 8;
            gP[j] = Wall + (size_t)(n0 + cb * 16 + (lane >> 2)) * K + ko;
            lP[j] = &smem[4096 + cb * 512];
        }
    }

    const int fr = lane & 15;
    const int fk = (lane >> 4) * 8;

    auto stage = [&](int buf, int k0) {
        const int off = buf * 12288;
#pragma unroll
        for (int j = 0; j < 3; ++j) {
            gload16(gP[j] + k0,      lP[j] + off);
            gload16(gP[j] + k0 + 32, lP[j] + off + 6144);
        }
    };

    stage(0, 0);
    __syncthreads();                         // drain prologue loads
    int cur = 0;
    for (int k0 = 0; k0 < K; k0 += 64) {
        if (k0 + 64 < K) stage(cur ^ 1, k0 + 64);
        const int off = cur * 12288;
#pragma unroll
        for (int half = 0; half < 2; ++half) {
            const int base = off + half * 6144;
            bf16x8 af[2], bf[4];
#pragma unroll
            for (int mt = 0; mt < 2; ++mt)
                af[mt] = *(const bf16x8*)&smem[base + (w * 32 + mt * 16 + fr) * 32 + fk];
#pragma unroll
            for (int nt = 0; nt < 4; ++nt)
                bf[nt] = *(const bf16x8*)&smem[base + 4096 + (nt * 16 + fr) * 32 + fk];
#pragma unroll
            for (int mt = 0; mt < 2; ++mt)
#pragma unroll
                for (int nt = 0; nt < 4; ++nt)
                    acc[mt][nt] = __builtin_amdgcn_mfma_f32_16x16x32_bf16(
                        af[mt], bf[nt], acc[mt][nt], 0, 0, 0);
        }
        __syncthreads();   // drains this iter's prefetch vmcnt + everyone's ds_reads
        cur ^= 1;
    }

    // ---- epilogue: stage 128x64 bf16 tile (stride 72), stream coalesced ----
#pragma unroll
    for (int mt = 0; mt < 2; ++mt)
#pragma unroll
        for (int nt = 0; nt < 4; ++nt) {
            const int col = nt * 16 + fr;
#pragma unroll
            for (int r = 0; r < 4; ++r) {
                const int rw = w * 32 + mt * 16 + (lane >> 4) * 4 + r;
                smem[rw * 72 + col] = f2bf(acc[mt][nt][r]);
            }
        }
    __syncthreads();
#pragma unroll
    for (int it = 0; it < 4; ++it) {
        const int j = it * 256 + tid;       // 0..1023 chunks of 8
        const int row = j >> 3, c8 = (j & 7) * 8;
        const int m = m0 + row;
        const int b = m >> 11, c = m & (C_ - 1);
        *(u16x8*)&Out[(((size_t)(b * H_ + h) * C_ + c) << 6) + c8] =
            *(const u16x8*)&smem[row * 72 + c8];
    }
}

// ---------------------------------------------------------------------------
// GEMM 2 (MFMA bf16), 128x64 tiles, BK=64, double-buffered prefetch (T3).
// united (4096x512) @ Wu^T-rows (1024x512) + bu -> new_out fp32
// ---------------------------------------------------------------------------
__global__ __launch_bounds__(256) void gemm_out_kernel(
    const uint16_t* __restrict__ U, const uint16_t* __restrict__ Wut,
    const float* __restrict__ bu, float* __restrict__ out)
{
    const int K = HD_;                      // 512
    const int m0 = blockIdx.y * 128;
    const int n0 = blockIdx.x * 64;         // N=1024

    __shared__ __align__(16) uint16_t smem[24576];   // 48 KB double buffer

    const int tid = threadIdx.x;
    const int w = tid >> 6, lane = tid & 63;

    f32x4 acc[2][4] = {};

    const uint16_t* gP[3];
    uint16_t* lP[3];
#pragma unroll
    for (int j = 0; j < 3; ++j) {
        const int ci = w * 3 + j;
        const int ko = (lane & 3) * 8;
        if (ci < 8) {
            gP[j] = U + (size_t)(m0 + ci * 16 + (lane >> 2)) * K + ko;
            lP[j] = &smem[ci * 512];
        } else {
            const int cb = ci - 8;
            gP[j] = Wut + (size_t)(n0 + cb * 16 + (lane >> 2)) * K + ko;
            lP[j] = &smem[4096 + cb * 512];
        }
    }

    const int fr = lane & 15;
    const int fk = (lane >> 4) * 8;

    auto stage = [&](int buf, int k0) {
        const int off = buf * 12288;
#pragma unroll
        for (int j = 0; j < 3; ++j) {
            gload16(gP[j] + k0,      lP[j] + off);
            gload16(gP[j] + k0 + 32, lP[j] + off + 6144);
        }
    };

    stage(0, 0);
    __syncthreads();
    int cur = 0;
    for (int k0 = 0; k0 < K; k0 += 64) {
        if (k0 + 64 < K) stage(cur ^ 1, k0 + 64);
        const int off = cur * 12288;
#pragma unroll
        for (int half = 0; half < 2; ++half) {
            const int base = off + half * 6144;
            bf16x8 af[2], bf[4];
#pragma unroll
            for (int mt = 0; mt < 2; ++mt)
                af[mt] = *(const bf16x8*)&smem[base + (w * 32 + mt * 16 + fr) * 32 + fk];
#pragma unroll
            for (int nt = 0; nt < 4; ++nt)
                bf[nt] = *(const bf16x8*)&smem[base + 4096 + (nt * 16 + fr) * 32 + fk];
#pragma unroll
            for (int mt = 0; mt < 2; ++mt)
#pragma unroll
                for (int nt = 0; nt < 4; ++nt)
                    acc[mt][nt] = __builtin_amdgcn_mfma_f32_16x16x32_bf16(
                        af[mt], bf[nt], acc[mt][nt], 0, 0, 0);
        }
        __syncthreads();
        cur ^= 1;
    }

#pragma unroll
    for (int mt = 0; mt < 2; ++mt) {
#pragma unroll
        for (int nt = 0; nt < 4; ++nt) {
            const int n = n0 + nt * 16 + fr;
            const float bias = bu[n];
#pragma unroll
            for (int r = 0; r < 4; ++r) {
                const int m = m0 + w * 32 + mt * 16 + (lane >> 4) * 4 + r;
                out[(size_t)m * E_ + n] = acc[mt][nt][r] + bias;
            }
        }
    }
}

// ---------------------------------------------------------------------------
// attention core.  One wave per (b,h,c) row; fused dense-row write via LDS
// (nontemporal stream ~ write roofline; sparse+memset was measured WORSE).
// Softmax weights wave-parallel on the (p = lane>>2, g = lane&3) layout.
// ---------------------------------------------------------------------------
__global__ __launch_bounds__(256) void attn_kernel(
    const float* __restrict__ means, const float* __restrict__ sigmas,
    const float* __restrict__ values, const float* __restrict__ S,
    const uint16_t* __restrict__ Qt, const uint16_t* __restrict__ Kt,
    const uint16_t* __restrict__ Vt, uint16_t* __restrict__ united,
    float* __restrict__ attn)
{
    __shared__ float rowbuf[4][2048];
    const int w = threadIdx.x >> 6;
    const int lane = threadIdx.x & 63;
    const int row = blockIdx.x * 4 + w;
    const int bh = row >> 11;
    const int c = row & (C_ - 1);
    const int b = bh >> 3;
    const int h = bh & 7;

    const float* mrow = means + (size_t)row * 8;
    const float4 ma = *(const float4*)(mrow);
    const float4 mb = *(const float4*)(mrow + 4);
    const float mm[8] = {ma.x, ma.y, ma.z, ma.w, mb.x, mb.y, mb.z, mb.w};

    int idx[16];
#pragma unroll
    for (int j = 0; j < 8; ++j) {
        int i0 = (int)floorf(mm[j]);
        i0 = min(max(i0, 0), C_ - 1);
        idx[2 * j] = i0;
        idx[2 * j + 1] = min(i0 + 1, C_ - 1);
    }

    // ---- (p,g) layout: p = point (lane>>2), g = quarter (lane&3) ----
    const int p = lane >> 2, g = lane & 3;
    int kidx = 0;
#pragma unroll
    for (int q = 0; q < 16; ++q)
        if (q == p) kidx = idx[q];

    // duplicate-point check for own p (wave-uniform idx[] in registers)
    bool dup = false;
#pragma unroll
    for (int q = 0; q < 15; ++q)
        dup = dup || ((q < p) && (idx[q] == kidx));

    // ---- per-point weight, parallel over (p, kk): lane handles kk=g,g+4 ----
    float mA = 0.f, mB = 0.f;
#pragma unroll
    for (int q = 0; q < 4; ++q)
        if (q == g) { mA = mm[q]; mB = mm[q + 4]; }
    const float* srow = sigmas + (size_t)row * 8;
    const float* vrow = values + (size_t)row * 8;
    const float* Sp = S + bh * 128 + p * 8;
    const float sgA = srow[g], sgB = srow[g + 4];
    const float vlA = vrow[g], vlB = vrow[g + 4];
    const float SvA = Sp[g],   SvB = Sp[g + 4];
    const float fi = (float)kidx;
    const float tA = (fi - mA) / sgA;
    const float tB = (fi - mB) / sgB;
    const float eA = expf(-0.5f * tA * tA);
    const float eB = expf(-0.5f * tB * tB);
    float wp = dup ? 0.0f
                   : fmaf(vlA, eA / (SvA + 1e-8f), vlB * eB / (SvB + 1e-8f));
    wp += __shfl_xor(wp, 1);
    wp += __shfl_xor(wp, 2);          // wp == wvp, replicated in 4-lane group

    // ---- Q.K dot: lane covers dims [g*16, g*16+16) of point p ----
    const uint16_t* Qrow = Qt + ((size_t)row << 6);
    const uint16_t* Krow = Kt + ((((size_t)bh << 11) + kidx) << 6);
    const u16x8 qa = *(const u16x8*)(Qrow + g * 16);
    const u16x8 qb = *(const u16x8*)(Qrow + g * 16 + 8);
    const u16x8 ka = *(const u16x8*)(Krow + g * 16);
    const u16x8 kb = *(const u16x8*)(Krow + g * 16 + 8);
    float dot = 0.0f;
#pragma unroll
    for (int j = 0; j < 8; ++j) {
        dot = fmaf(bf2f(qa[j]), bf2f(ka[j]), dot);
        dot = fmaf(bf2f(qb[j]), bf2f(kb[j]), dot);
    }
    dot += __shfl_xor(dot, 1);
    dot += __shfl_xor(dot, 2);

    const float logit = wp * dot;

    float mx = logit;
#pragma unroll
    for (int off = 4; off < 64; off <<= 1)
        mx = fmaxf(mx, __shfl_xor(mx, off));
    const float e = expf(logit - mx);
    float se = e;
#pragma unroll
    for (int off = 4; off < 64; off <<= 1)
        se += __shfl_xor(se, off);
    const float sm = e / se;

    float smv[16];
#pragma unroll
    for (int q = 0; q < 16; ++q)
        smv[q] = __shfl(sm, q * 4);

    // ---- V combine (lane = d) ----
    const uint16_t* Vbh = Vt + ((size_t)bh << 17);
    float acc = 0.0f;
#pragma unroll
    for (int q = 0; q < 16; ++q)
        acc = fmaf(bf2f(Vbh[((size_t)idx[q] << 6) + lane]), smv[q], acc);
    united[((size_t)(b * C_ + c)) * HD_ + h * 64 + lane] = f2bf(acc);

    // ---- attentions row: zero LDS, scatter-add, nontemporal stream out ----
    const f32x4 z4 = {0.f, 0.f, 0.f, 0.f};
#pragma unroll
    for (int j = 0; j < 8; ++j)
        *(f32x4*)&rowbuf[w][(j * 64 + lane) * 4] = z4;
    __syncthreads();
    if (g == 0) atomicAdd(&rowbuf[w][kidx], sm);   // one lane per point p
    __syncthreads();
    float* arow = attn + ((size_t)row << 11);
#pragma unroll
    for (int j = 0; j < 8; ++j) {
        const int o = (j * 64 + lane) * 4;
        __builtin_nontemporal_store(*(const f32x4*)&rowbuf[w][o], (f32x4*)&arow[o]);
    }
}

// ---------------------------------------------------------------------------
extern "C" void kernel_launch(void* const* d_in, const int* in_sizes, int n_in,
                              void* d_out, int out_size, void* d_ws,
                              size_t ws_size, hipStream_t stream) {
    const float* x      = (const float*)d_in[0];
    const float* means  = (const float*)d_in[2];
    const float* sigmas = (const float*)d_in[3];
    const float* values = (const float*)d_in[4];
    const float* Wk     = (const float*)d_in[5];
    const float* Wq     = (const float*)d_in[6];
    const float* Wv     = (const float*)d_in[7];
    const float* Wu     = (const float*)d_in[8];
    const float* bu     = (const float*)d_in[9];

    float* out  = (float*)d_out;
    float* attn = out + (size_t)M_ * E_;

    uint16_t* wsp = (uint16_t*)d_ws;
    uint16_t* xb     = wsp;                              // 4194304
    uint16_t* Wall   = xb + 4194304;                     // 1572864 (1536x1024)
    uint16_t* Wut    = Wall + 1572864;                   // 524288
    uint16_t* Qt     = Wut + 524288;                     // 2097152
    uint16_t* Kt     = Qt + 2097152;
    uint16_t* Vt     = Kt + 2097152;
    uint16_t* united = Vt + 2097152;                     // 2097152
    float*    S      = (float*)(united + 2097152);       // 2048 floats

    (void)hipMemsetAsync(S, 0, 2048 * sizeof(float), stream);

    prep_kernel<<<4224, 256, 0, stream>>>(
        x, Wq, Wk, Wv, Wu, means, sigmas, xb, Wall, Wut, S);
    gemm_qkv_kernel<<<dim3(24, 32), 256, 0, stream>>>(xb, Wall, Qt, Kt, Vt);
    attn_kernel<<<ROWS_ / 4, 256, 0, stream>>>(
        means, sigmas, values, S, Qt, Kt, Vt, united, attn);
    gemm_out_kernel<<<dim3(16, 32), 256, 0, stream>>>(united, Wut, bu, out);
}

// Round 6
// 379.601 us; speedup vs baseline: 1.1859x; 1.0143x over previous
//
#include <hip/hip_runtime.h>
#include <math.h>
#include <stdint.h>

#define B_ 2
#define H_ 8
#define C_ 2048
#define E_ 1024
#define D_ 64
#define KP_ 8
#define P_ 16
#define HD_ 512              // H*D
#define ROWS_ 32768          // B*H*C
#define M_ 4096              // B*C

typedef __bf16 bf16x8 __attribute__((ext_vector_type(8)));
typedef float f32x4 __attribute__((ext_vector_type(4)));
typedef uint16_t u16x8 __attribute__((ext_vector_type(8)));

__device__ inline uint16_t f2bf(float f) {
    union { float f; uint32_t u; } v; v.f = f;
    uint32_t u = v.u + 0x7FFF + ((v.u >> 16) & 1);   // RNE
    return (uint16_t)(u >> 16);
}
__device__ inline float bf2f(uint16_t h) {
    union { uint32_t u; float f; } v; v.u = ((uint32_t)h) << 16;
    return v.f;
}

// async global->LDS, 16B per lane; LDS dest = wave-uniform base + lane*16
__device__ inline void gload16(const uint16_t* g, uint16_t* l) {
    __builtin_amdgcn_global_load_lds(
        (const __attribute__((address_space(1))) void*)g,
        (__attribute__((address_space(3))) void*)l, 16, 0, 0);
}

// ---------------------------------------------------------------------------
// prep kernel: x-convert, weight transpose-convert, density context-sums.
//   blocks [0, 2048)      : convert x (fp32 -> bf16), 8 elem/thread
//   blocks [2048, 4096)   : transpose-convert one 32x32 weight tile
//   blocks [4096, 4224)   : density sums (one thread per (b,h,c) row)
//     butterfly recursive-halving reduce, block-level LDS combine.
// ---------------------------------------------------------------------------
__global__ __launch_bounds__(256) void prep_kernel(
    const float* __restrict__ x,
    const float* __restrict__ Wq, const float* __restrict__ Wk,
    const float* __restrict__ Wv, const float* __restrict__ Wu,
    const float* __restrict__ means, const float* __restrict__ sigmas,
    uint16_t* __restrict__ xb, uint16_t* __restrict__ Wall,
    uint16_t* __restrict__ Wut, float* __restrict__ S)
{
    const int bx = blockIdx.x;
    if (bx < 2048) {
        const int i = (bx * 256 + threadIdx.x) * 8;
        const float4 a = *(const float4*)(x + i);
        const float4 b = *(const float4*)(x + i + 4);
        u16x8 o;
        o[0] = f2bf(a.x); o[1] = f2bf(a.y); o[2] = f2bf(a.z); o[3] = f2bf(a.w);
        o[4] = f2bf(b.x); o[5] = f2bf(b.y); o[6] = f2bf(b.z); o[7] = f2bf(b.w);
        *(u16x8*)(xb + i) = o;
        return;
    }
    if (bx < 4096) {
        const int t = bx - 2048;
        const int z = t >> 9;
        const float* in; uint16_t* out; int R, Cc; float scale;
        if (z == 0)      { in = Wq; out = Wall;               R = E_;  Cc = HD_; scale = 0.125f; }
        else if (z == 1) { in = Wk; out = Wall + 512 * 1024;  R = E_;  Cc = HD_; scale = 0.125f; }
        else if (z == 2) { in = Wv; out = Wall + 1024 * 1024; R = E_;  Cc = HD_; scale = 1.0f; }
        else             { in = Wu; out = Wut;                R = HD_; Cc = E_;  scale = 1.0f; }
        const int tiles_x = Cc >> 5;
        const int ti = t & 511;
        const int tx = ti % tiles_x;
        const int ty = ti / tiles_x;
        const int r0 = ty * 32, c0 = tx * 32;
        __shared__ float tbuf[32][33];
        const int lx = threadIdx.x & 31, ly = threadIdx.x >> 5;
#pragma unroll
        for (int i = 0; i < 4; ++i)
            tbuf[ly * 4 + i][lx] = in[(size_t)(r0 + ly * 4 + i) * Cc + c0 + lx];
        __syncthreads();
#pragma unroll
        for (int i = 0; i < 4; ++i)
            out[(size_t)(c0 + ly * 4 + i) * R + r0 + lx] =
                f2bf(tbuf[lx][ly * 4 + i] * scale);
        return;
    }
    // ---- density sums ----
    const int row = (bx - 4096) * 256 + threadIdx.x;
    const int lane = threadIdx.x & 63;
    const int bh = row >> 11;          // constant per block (256 rows/block)

    __shared__ float Sacc[128];
    if (threadIdx.x < 128) Sacc[threadIdx.x] = 0.0f;
    __syncthreads();

    const float* mrow = means + (size_t)row * 8;
    const float* srow = sigmas + (size_t)row * 8;
    const float4 ma = *(const float4*)(mrow);
    const float4 mb = *(const float4*)(mrow + 4);
    const float4 sa = *(const float4*)(srow);
    const float4 sb = *(const float4*)(srow + 4);
    const float mm[8] = {ma.x, ma.y, ma.z, ma.w, mb.x, mb.y, mb.z, mb.w};
    const float sg[8] = {sa.x, sa.y, sa.z, sa.w, sb.x, sb.y, sb.z, sb.w};

    int idx[16];
#pragma unroll
    for (int j = 0; j < 8; ++j) {
        int i0 = (int)floorf(mm[j]);
        i0 = min(max(i0, 0), C_ - 1);
        idx[2 * j] = i0;
        idx[2 * j + 1] = min(i0 + 1, C_ - 1);
    }
    unsigned dupm = 0;
#pragma unroll
    for (int p = 1; p < 16; ++p) {
        bool d = false;
#pragma unroll
        for (int q = 0; q < 15; ++q)
            if (q < p) d = d || (idx[q] == idx[p]);
        if (d) dupm |= (1u << p);
    }

    // lane's final slot after the 6-stage butterfly is bitrev6(lane)
    const int rev = ((lane & 1) << 5) | ((lane & 2) << 3) | ((lane & 4) << 1) |
                    ((lane & 8) >> 1) | ((lane & 16) >> 3) | ((lane & 32) >> 5);

#pragma unroll
    for (int ph = 0; ph < 2; ++ph) {
        float a[64];
#pragma unroll
        for (int j = 0; j < 64; ++j) {
            const int p = ph * 8 + (j >> 3);
            const int kk = j & 7;
            const float fi = (float)idx[p];
            const float t = (fi - mm[kk]) / sg[kk];
            const float e = expf(-0.5f * t * t);
            a[j] = ((dupm >> p) & 1u) ? 0.0f : e;
        }
        // recursive halving: stage b keeps 32>>b values; lane keeps the
        // (lane>>b)&1 half of its current range, exchanges the other half.
#pragma unroll
        for (int b = 0; b < 6; ++b) {
            const int n = 32 >> b;
            const bool hi = (lane >> b) & 1;
#pragma unroll
            for (int j = 0; j < n; ++j) {
                float send = hi ? a[j] : a[j + n];
                float recv = __shfl_xor(send, 1 << b);
                a[j] = (hi ? a[j + n] : a[j]) + recv;
            }
        }
        atomicAdd(&Sacc[ph * 64 + rev], a[0]);
    }
    __syncthreads();
    if (threadIdx.x < 128)
        atomicAdd(&S[bh * 128 + threadIdx.x], Sacc[threadIdx.x]);
}

// ---------------------------------------------------------------------------
// Fused QKV GEMM (MFMA bf16), 128x64 tiles, BK=64, double-buffered prefetch.
// (R5 A/B vs serial: neutral -> GEMMs are not the bottleneck; kept as-is.)
// ---------------------------------------------------------------------------
__global__ __launch_bounds__(256) void gemm_qkv_kernel(
    const uint16_t* __restrict__ xb, const uint16_t* __restrict__ Wall,
    uint16_t* __restrict__ Qt, uint16_t* __restrict__ Kt,
    uint16_t* __restrict__ Vt)
{
    const int K = E_;                       // 1024
    const int m0 = blockIdx.y * 128;
    const int n0 = blockIdx.x * 64;         // 0..1535
    const int z = n0 >> 9;
    uint16_t* __restrict__ Out = (z == 0) ? Qt : (z == 1) ? Kt : Vt;
    const int h = (n0 & 511) >> 6;          // single head per block

    __shared__ __align__(16) uint16_t smem[24576];   // 48 KB, 3 blocks/CU

    const int tid = threadIdx.x;
    const int w = tid >> 6, lane = tid & 63;

    f32x4 acc[2][4] = {};

    const uint16_t* gP[3];
    uint16_t* lP[3];
#pragma unroll
    for (int j = 0; j < 3; ++j) {
        const int ci = w * 3 + j;
        const int rr = (ci & 7) * 16 + (lane >> 2);   // works for both halves
        const int ko = (lane & 3) * 8;
        if (ci < 8) {
            gP[j] = xb + (size_t)(m0 + rr) * K + ko;
            lP[j] = &smem[ci * 512];
        } else {
            const int cb = ci - 8;
            gP[j] = Wall + (size_t)(n0 + cb * 16 + (lane >> 2)) * K + ko;
            lP[j] = &smem[4096 + cb * 512];
        }
    }

    const int fr = lane & 15;
    const int fk = (lane >> 4) * 8;

    auto stage = [&](int buf, int k0) {
        const int off = buf * 12288;
#pragma unroll
        for (int j = 0; j < 3; ++j) {
            gload16(gP[j] + k0,      lP[j] + off);
            gload16(gP[j] + k0 + 32, lP[j] + off + 6144);
        }
    };

    stage(0, 0);
    __syncthreads();                         // drain prologue loads
    int cur = 0;
    for (int k0 = 0; k0 < K; k0 += 64) {
        if (k0 + 64 < K) stage(cur ^ 1, k0 + 64);
        const int off = cur * 12288;
#pragma unroll
        for (int half = 0; half < 2; ++half) {
            const int base = off + half * 6144;
            bf16x8 af[2], bf[4];
#pragma unroll
            for (int mt = 0; mt < 2; ++mt)
                af[mt] = *(const bf16x8*)&smem[base + (w * 32 + mt * 16 + fr) * 32 + fk];
#pragma unroll
            for (int nt = 0; nt < 4; ++nt)
                bf[nt] = *(const bf16x8*)&smem[base + 4096 + (nt * 16 + fr) * 32 + fk];
#pragma unroll
            for (int mt = 0; mt < 2; ++mt)
#pragma unroll
                for (int nt = 0; nt < 4; ++nt)
                    acc[mt][nt] = __builtin_amdgcn_mfma_f32_16x16x32_bf16(
                        af[mt], bf[nt], acc[mt][nt], 0, 0, 0);
        }
        __syncthreads();   // drains this iter's prefetch vmcnt + everyone's ds_reads
        cur ^= 1;
    }

    // ---- epilogue: stage 128x64 bf16 tile (stride 72), stream coalesced ----
#pragma unroll
    for (int mt = 0; mt < 2; ++mt)
#pragma unroll
        for (int nt = 0; nt < 4; ++nt) {
            const int col = nt * 16 + fr;
#pragma unroll
            for (int r = 0; r < 4; ++r) {
                const int rw = w * 32 + mt * 16 + (lane >> 4) * 4 + r;
                smem[rw * 72 + col] = f2bf(acc[mt][nt][r]);
            }
        }
    __syncthreads();
#pragma unroll
    for (int it = 0; it < 4; ++it) {
        const int j = it * 256 + tid;       // 0..1023 chunks of 8
        const int row = j >> 3, c8 = (j & 7) * 8;
        const int m = m0 + row;
        const int b = m >> 11, c = m & (C_ - 1);
        *(u16x8*)&Out[(((size_t)(b * H_ + h) * C_ + c) << 6) + c8] =
            *(const u16x8*)&smem[row * 72 + c8];
    }
}

// ---------------------------------------------------------------------------
// GEMM 2 (MFMA bf16), 128x64 tiles, BK=64, double-buffered prefetch.
// united (4096x512) @ Wu^T-rows (1024x512) + bu -> new_out fp32
// ---------------------------------------------------------------------------
__global__ __launch_bounds__(256) void gemm_out_kernel(
    const uint16_t* __restrict__ U, const uint16_t* __restrict__ Wut,
    const float* __restrict__ bu, float* __restrict__ out)
{
    const int K = HD_;                      // 512
    const int m0 = blockIdx.y * 128;
    const int n0 = blockIdx.x * 64;         // N=1024

    __shared__ __align__(16) uint16_t smem[24576];   // 48 KB double buffer

    const int tid = threadIdx.x;
    const int w = tid >> 6, lane = tid & 63;

    f32x4 acc[2][4] = {};

    const uint16_t* gP[3];
    uint16_t* lP[3];
#pragma unroll
    for (int j = 0; j < 3; ++j) {
        const int ci = w * 3 + j;
        const int ko = (lane & 3) * 8;
        if (ci < 8) {
            gP[j] = U + (size_t)(m0 + ci * 16 + (lane >> 2)) * K + ko;
            lP[j] = &smem[ci * 512];
        } else {
            const int cb = ci - 8;
            gP[j] = Wut + (size_t)(n0 + cb * 16 + (lane >> 2)) * K + ko;
            lP[j] = &smem[4096 + cb * 512];
        }
    }

    const int fr = lane & 15;
    const int fk = (lane >> 4) * 8;

    auto stage = [&](int buf, int k0) {
        const int off = buf * 12288;
#pragma unroll
        for (int j = 0; j < 3; ++j) {
            gload16(gP[j] + k0,      lP[j] + off);
            gload16(gP[j] + k0 + 32, lP[j] + off + 6144);
        }
    };

    stage(0, 0);
    __syncthreads();
    int cur = 0;
    for (int k0 = 0; k0 < K; k0 += 64) {
        if (k0 + 64 < K) stage(cur ^ 1, k0 + 64);
        const int off = cur * 12288;
#pragma unroll
        for (int half = 0; half < 2; ++half) {
            const int base = off + half * 6144;
            bf16x8 af[2], bf[4];
#pragma unroll
            for (int mt = 0; mt < 2; ++mt)
                af[mt] = *(const bf16x8*)&smem[base + (w * 32 + mt * 16 + fr) * 32 + fk];
#pragma unroll
            for (int nt = 0; nt < 4; ++nt)
                bf[nt] = *(const bf16x8*)&smem[base + 4096 + (nt * 16 + fr) * 32 + fk];
#pragma unroll
            for (int mt = 0; mt < 2; ++mt)
#pragma unroll
                for (int nt = 0; nt < 4; ++nt)
                    acc[mt][nt] = __builtin_amdgcn_mfma_f32_16x16x32_bf16(
                        af[mt], bf[nt], acc[mt][nt], 0, 0, 0);
        }
        __syncthreads();
        cur ^= 1;
    }

#pragma unroll
    for (int mt = 0; mt < 2; ++mt) {
#pragma unroll
        for (int nt = 0; nt < 4; ++nt) {
            const int n = n0 + nt * 16 + fr;
            const float bias = bu[n];
#pragma unroll
            for (int r = 0; r < 4; ++r) {
                const int m = m0 + w * 32 + mt * 16 + (lane >> 4) * 4 + r;
                out[(size_t)m * E_ + n] = acc[mt][nt][r] + bias;
            }
        }
    }
}

// ---------------------------------------------------------------------------
// attention core.  One wave per (b,h,c) row.
// NEW (T1): bijective XCD swizzle of blockIdx -> each XCD gets 1024
// contiguous blocks = 2 bh slices = 1 MB K/V working set, L2-resident
// (default round-robin spreads the same K/V lines over all 8 per-XCD L2s,
// 8x duplicated L3 fills on 134 MB of gather traffic).
// NEW: Q/K/V gathers hoisted to right after idx -> gather latency hides
// under the weight/expf/softmax VALU chain.
// ---------------------------------------------------------------------------
__global__ __launch_bounds__(256) void attn_kernel(
    const float* __restrict__ means, const float* __restrict__ sigmas,
    const float* __restrict__ values, const float* __restrict__ S,
    const uint16_t* __restrict__ Qt, const uint16_t* __restrict__ Kt,
    const uint16_t* __restrict__ Vt, uint16_t* __restrict__ united,
    float* __restrict__ attn)
{
    __shared__ float rowbuf[4][2048];
    const int w = threadIdx.x >> 6;
    const int lane = threadIdx.x & 63;
    // XCD-aware swizzle: 8192 blocks, 8 XCDs, 1024 contiguous per XCD.
    const int bid = blockIdx.x;
    const int swz = (bid & 7) * 1024 + (bid >> 3);
    const int row = swz * 4 + w;
    const int bh = row >> 11;
    const int c = row & (C_ - 1);
    const int b = bh >> 3;
    const int h = bh & 7;

    const float* mrow = means + (size_t)row * 8;
    const float4 ma = *(const float4*)(mrow);
    const float4 mb = *(const float4*)(mrow + 4);
    const float mm[8] = {ma.x, ma.y, ma.z, ma.w, mb.x, mb.y, mb.z, mb.w};

    int idx[16];
#pragma unroll
    for (int j = 0; j < 8; ++j) {
        int i0 = (int)floorf(mm[j]);
        i0 = min(max(i0, 0), C_ - 1);
        idx[2 * j] = i0;
        idx[2 * j + 1] = min(i0 + 1, C_ - 1);
    }

    // ---- (p,g) layout: p = point (lane>>2), g = quarter (lane&3) ----
    const int p = lane >> 2, g = lane & 3;
    int kidx = 0;
#pragma unroll
    for (int q = 0; q < 16; ++q)
        if (q == p) kidx = idx[q];

    // ---- EARLY ISSUE: all global gathers, addresses depend only on idx ----
    const uint16_t* Qrow = Qt + ((size_t)row << 6);
    const uint16_t* Krow = Kt + ((((size_t)bh << 11) + kidx) << 6);
    const u16x8 qa = *(const u16x8*)(Qrow + g * 16);
    const u16x8 qb = *(const u16x8*)(Qrow + g * 16 + 8);
    const u16x8 ka = *(const u16x8*)(Krow + g * 16);
    const u16x8 kb = *(const u16x8*)(Krow + g * 16 + 8);
    const uint16_t* Vbh = Vt + ((size_t)bh << 17);
    uint16_t vv[16];
#pragma unroll
    for (int q = 0; q < 16; ++q)
        vv[q] = Vbh[((size_t)idx[q] << 6) + lane];

    // duplicate-point check for own p (wave-uniform idx[] in registers)
    bool dup = false;
#pragma unroll
    for (int q = 0; q < 15; ++q)
        dup = dup || ((q < p) && (idx[q] == kidx));

    // ---- per-point weight, parallel over (p, kk): lane handles kk=g,g+4 ----
    float mA = 0.f, mB = 0.f;
#pragma unroll
    for (int q = 0; q < 4; ++q)
        if (q == g) { mA = mm[q]; mB = mm[q + 4]; }
    const float* srow = sigmas + (size_t)row * 8;
    const float* vrow = values + (size_t)row * 8;
    const float* Sp = S + bh * 128 + p * 8;
    const float sgA = srow[g], sgB = srow[g + 4];
    const float vlA = vrow[g], vlB = vrow[g + 4];
    const float SvA = Sp[g],   SvB = Sp[g + 4];
    const float fi = (float)kidx;
    const float tA = (fi - mA) / sgA;
    const float tB = (fi - mB) / sgB;
    const float eA = expf(-0.5f * tA * tA);
    const float eB = expf(-0.5f * tB * tB);
    float wp = dup ? 0.0f
                   : fmaf(vlA, eA / (SvA + 1e-8f), vlB * eB / (SvB + 1e-8f));
    wp += __shfl_xor(wp, 1);
    wp += __shfl_xor(wp, 2);          // wp == wvp, replicated in 4-lane group

    // ---- Q.K dot: lane covers dims [g*16, g*16+16) of point p ----
    float dot = 0.0f;
#pragma unroll
    for (int j = 0; j < 8; ++j) {
        dot = fmaf(bf2f(qa[j]), bf2f(ka[j]), dot);
        dot = fmaf(bf2f(qb[j]), bf2f(kb[j]), dot);
    }
    dot += __shfl_xor(dot, 1);
    dot += __shfl_xor(dot, 2);

    const float logit = wp * dot;

    float mx = logit;
#pragma unroll
    for (int off = 4; off < 64; off <<= 1)
        mx = fmaxf(mx, __shfl_xor(mx, off));
    const float e = expf(logit - mx);
    float se = e;
#pragma unroll
    for (int off = 4; off < 64; off <<= 1)
        se += __shfl_xor(se, off);
    const float sm = e / se;

    float smv[16];
#pragma unroll
    for (int q = 0; q < 16; ++q)
        smv[q] = __shfl(sm, q * 4);

    // ---- V combine (lane = d) with preloaded vv ----
    float acc = 0.0f;
#pragma unroll
    for (int q = 0; q < 16; ++q)
        acc = fmaf(bf2f(vv[q]), smv[q], acc);
    united[((size_t)(b * C_ + c)) * HD_ + h * 64 + lane] = f2bf(acc);

    // ---- attentions row: zero LDS, scatter-add, nontemporal stream out ----
    const f32x4 z4 = {0.f, 0.f, 0.f, 0.f};
#pragma unroll
    for (int j = 0; j < 8; ++j)
        *(f32x4*)&rowbuf[w][(j * 64 + lane) * 4] = z4;
    __syncthreads();
    if (g == 0) atomicAdd(&rowbuf[w][kidx], sm);   // one lane per point p
    __syncthreads();
    float* arow = attn + ((size_t)row << 11);
#pragma unroll
    for (int j = 0; j < 8; ++j) {
        const int o = (j * 64 + lane) * 4;
        __builtin_nontemporal_store(*(const f32x4*)&rowbuf[w][o], (f32x4*)&arow[o]);
    }
}

// ---------------------------------------------------------------------------
extern "C" void kernel_launch(void* const* d_in, const int* in_sizes, int n_in,
                              void* d_out, int out_size, void* d_ws,
                              size_t ws_size, hipStream_t stream) {
    const float* x      = (const float*)d_in[0];
    const float* means  = (const float*)d_in[2];
    const float* sigmas = (const float*)d_in[3];
    const float* values = (const float*)d_in[4];
    const float* Wk     = (const float*)d_in[5];
    const float* Wq     = (const float*)d_in[6];
    const float* Wv     = (const float*)d_in[7];
    const float* Wu     = (const float*)d_in[8];
    const float* bu     = (const float*)d_in[9];

    float* out  = (float*)d_out;
    float* attn = out + (size_t)M_ * E_;

    uint16_t* wsp = (uint16_t*)d_ws;
    uint16_t* xb     = wsp;                              // 4194304
    uint16_t* Wall   = xb + 4194304;                     // 1572864 (1536x1024)
    uint16_t* Wut    = Wall + 1572864;                   // 524288
    uint16_t* Qt     = Wut + 524288;                     // 2097152
    uint16_t* Kt     = Qt + 2097152;
    uint16_t* Vt     = Kt + 2097152;
    uint16_t* united = Vt + 2097152;                     // 2097152
    float*    S      = (float*)(united + 2097152);       // 2048 floats

    (void)hipMemsetAsync(S, 0, 2048 * sizeof(float), stream);

    prep_kernel<<<4224, 256, 0, stream>>>(
        x, Wq, Wk, Wv, Wu, means, sigmas, xb, Wall, Wut, S);
    gemm_qkv_kernel<<<dim3(24, 32), 256, 0, stream>>>(xb, Wall, Qt, Kt, Vt);
    attn_kernel<<<ROWS_ / 4, 256, 0, stream>>>(
        means, sigmas, values, S, Qt, Kt, Vt, united, attn);
    gemm_out_kernel<<<dim3(16, 32), 256, 0, stream>>>(united, Wut, bu, out);
}